// Round 14
// baseline (154.356 us; speedup 1.0000x reference)
//
#include <hip/hip_runtime.h>
#include <hip/hip_bf16.h>

// EvoAttn: causal self-attention with Q=K=V = x.reshape(B,L,H,D).
// B=2 H=16 L=2048 D=128, fp32 in/out, bf16 MFMA compute.
// v14: 512-thr blocks = 8 waves covering TWO q-tiles (pair 2j,2j+1) that
//      SHARE one ascending k-tile stream (staging bytes/wave halve);
//      16 waves/CU (v9's per-wave shape kept: 104 VGPR). Q loaded from
//      global fragment region at prologue. ZIG-balanced block lengths.

#define TL 2048
#define TE 2048
#define TD 128
#define KB 64
#define NTILES 32                          // TL / KB
#define TILE_B 16384                       // 64*128*2 bytes
#define KV_REGION (32 * NTILES * TILE_B)   // 16 MB per layout
#define WS_NEED (2u * (unsigned)KV_REGION) // 32 MB

typedef __attribute__((ext_vector_type(8))) short bf16x8;
typedef __attribute__((ext_vector_type(4))) float f32x4;
typedef __attribute__((ext_vector_type(8))) unsigned short u16x8;
typedef __attribute__((ext_vector_type(4))) unsigned short u16x4;

// (1/sqrt(128)) * log2(e)
#define SCALE_LOG2E 0.12751879f

__device__ __forceinline__ unsigned short f2bf(float f) {
  __hip_bfloat16 h = __float2bfloat16(f);
  return __builtin_bit_cast(unsigned short, h);
}

__device__ __forceinline__ f32x4 mfma16(bf16x8 a, bf16x8 b, f32x4 c) {
  return __builtin_amdgcn_mfma_f32_16x16x32_bf16(a, b, c, 0, 0, 0);
}

__device__ __forceinline__ void gl_lds16(const void* g, void* l) {
  __builtin_amdgcn_global_load_lds(
      (__attribute__((address_space(1))) void*)(g),
      (__attribute__((address_space(3))) void*)(l), 16, 0, 0);
}

// ws layout (per tile bid = bh*32 + kt):
// K region: 16B frag (kt2,c,g,q15) at ((kt2*4+c)*64 + g*16 + q15)*16
//   holding K[kt2*16+q15][c*32+g*8 .. +8).
// V region: 16B frag (half,dt,g,q15) at ((half*8+dt)*64 + g*16 + q15)*16
//   holding V[k=half*32+g*8+j][d=dt*16+q15].
__global__ void __launch_bounds__(256)
prepack(const float* __restrict__ x, char* __restrict__ wsb) {
  const int bid = blockIdx.x;            // bh*32 + kt
  const int kt = bid & 31;
  const int bh = bid >> 5;
  const int b = bh >> 4;
  const int h = bh & 15;
  const float* src = x + (size_t)b * TL * TE + h * TD + (size_t)kt * KB * TE;
  const int t = threadIdx.x;
  const int kr = (t >> 4) << 2;          // 4 consecutive k-rows
  const int d0 = (t & 15) << 3;          // 8 d-cols
  unsigned short c[4][8];
#pragma unroll
  for (int rr = 0; rr < 4; ++rr) {
    const float* p = src + (kr + rr) * TE + d0;
    const float4 a = *(const float4*)p;
    const float4 bb = *(const float4*)(p + 4);
    c[rr][0] = f2bf(a.x);  c[rr][1] = f2bf(a.y);  c[rr][2] = f2bf(a.z);  c[rr][3] = f2bf(a.w);
    c[rr][4] = f2bf(bb.x); c[rr][5] = f2bf(bb.y); c[rr][6] = f2bf(bb.z); c[rr][7] = f2bf(bb.w);
  }
  // K fragment order
  char* gkv = wsb + (size_t)bid * TILE_B;
  const int kt2 = kr >> 4;
  const int q0r = kr & 15;
  const int cc_ = (t & 15) >> 2;
  const int gg_ = (t & 15) & 3;
#pragma unroll
  for (int rr = 0; rr < 4; ++rr) {
    u16x8 o = {c[rr][0], c[rr][1], c[rr][2], c[rr][3],
               c[rr][4], c[rr][5], c[rr][6], c[rr][7]};
    const int off = (((kt2 * 4 + cc_) * 64 + gg_ * 16 + (q0r + rr)) << 4);
    *(u16x8*)(gkv + off) = o;
  }
  // V fragment order
  char* gkt = wsb + KV_REGION + (size_t)bid * TILE_B;
  const int half = kr >> 5;
  const int g = (kr >> 3) & 3;
  const int j0 = kr & 7;                 // 0 or 4
#pragma unroll
  for (int cc = 0; cc < 8; ++cc) {
    const int d = d0 + cc;
    u16x4 o = {c[0][cc], c[1][cc], c[2][cc], c[3][cc]};   // k = kr..kr+3
    const int off = (((half * 8 + (d >> 4)) * 64 + g * 16 + (d & 15)) << 4) + j0 * 2;
    *(u16x4*)(gkt + off) = o;
  }
}

// ------- main kernel: 8 waves, two q-tiles (2j, 2j+1), shared k stream ------
__global__ void __launch_bounds__(512)
evo_attn7(const char* __restrict__ wsb, float* __restrict__ out) {
  // kv0 | kv1 | kvt | pl(8 waves x 2KB) = 64 KB -> 2 blocks/CU
  __shared__ char smem[4 * TILE_B];

  const int t = threadIdx.x;
  const int lane = t & 63;
  const int w = t >> 6;        // wave 0..7
  const int g = lane >> 4;
  const int q15 = lane & 15;
  const int kt2q = w & 3;      // q-row group within this wave's q-tile

  const int blk = blockIdx.x;            // 512 blocks
  const int bh = (blk & 7) * 4 + (blk >> 7);   // XCD-affine
  const int ZIG[16] = {15, 0, 13, 2, 11, 4, 9, 6, 8, 7, 10, 5, 12, 3, 14, 1};
  const int pj = ZIG[(blk >> 3) & 15];   // pair index: q-tiles 2pj, 2pj+1
  const int b = bh >> 4;
  const int h = bh & 15;
  const int nsteps = 2 * pj + 2;
  const int qtg = 2 * pj + ((w < 4) ? 1 : 0);  // this wave-group's q-tile

  const char* gkv = wsb + (size_t)bh * (NTILES * TILE_B);
  const char* gkt = wsb + KV_REGION + (size_t)bh * (NTILES * TILE_B);
  char* plw = smem + 3 * TILE_B + w * 2048;
  const char* kvtb = smem + 2 * TILE_B;
  const int l16 = lane * 16;

  // 512 threads stage one 16KB tile: 2 gl_lds16/thread; LDS dest is
  // wave-uniform base + lane*16 -> each wave a 2KB region.
#define STAGE_KV(BUFI, KT)                                                 \
  {                                                                        \
    char* dst_ = smem + (BUFI) * TILE_B + w * 2048;                        \
    const char* src_ = gkv + (size_t)(KT) * TILE_B + w * 2048 + l16;       \
    gl_lds16(src_, dst_);                                                  \
    gl_lds16(src_ + 1024, dst_ + 1024);                                    \
  }
#define STAGE_KVT(KT)                                                      \
  {                                                                        \
    char* dst_ = smem + 2 * TILE_B + w * 2048;                             \
    const char* src_ = gkt + (size_t)(KT) * TILE_B + w * 2048 + l16;       \
    gl_lds16(src_, dst_);                                                  \
    gl_lds16(src_ + 1024, dst_ + 1024);                                    \
  }

  // prologue: tiles 0,1 (kv) + tile 0 (kvt); Q frags straight from global
  STAGE_KV(0, 0);
  STAGE_KV(1, 1);          // nsteps >= 2 always
  STAGE_KVT(0);
  bf16x8 qf[4];
  {
    const char* qsrc = gkv + (size_t)qtg * TILE_B;
#pragma unroll
    for (int c = 0; c < 4; ++c)
      qf[c] = *(const bf16x8*)(qsrc + (kt2q * 4 + c) * 1024 + l16);
  }
  asm volatile("s_waitcnt vmcnt(0)" ::: "memory");
  __builtin_amdgcn_s_barrier();
  asm volatile("" ::: "memory");

  f32x4 acc[8];
#pragma unroll
  for (int dt = 0; dt < 8; ++dt) acc[dt] = (f32x4){0.f, 0.f, 0.f, 0.f};
  float mrun = -1e30f;   // raw score domain
  float lrun = 0.f;

  for (int s = 0; s < nsteps; ++s) {
    if (s > 0) {  // kv(s) ready: drain all but [kvt(s):2, kv(s+1):2?]
      if (s + 1 < nsteps) asm volatile("s_waitcnt vmcnt(4)" ::: "memory");
      else                asm volatile("s_waitcnt vmcnt(2)" ::: "memory");
      __builtin_amdgcn_s_barrier();
      asm volatile("" ::: "memory");
    }
    const char* kv = smem + (s & 1) * TILE_B;
    const bool active = (s <= qtg);

    float pf[16];
    if (active) {
      // QK^T: lane (g,q15) holds S[k=kt2*16+g*4+r][q=16*kt2q+q15] (raw)
      __builtin_amdgcn_s_setprio(1);
#pragma unroll
      for (int kt2 = 0; kt2 < 4; ++kt2) {
        f32x4 st = (f32x4){0.f, 0.f, 0.f, 0.f};
#pragma unroll
        for (int c = 0; c < 4; ++c) {
          bf16x8 kf = *(const bf16x8*)(kv + (kt2 * 4 + c) * 1024 + l16);
          st = mfma16(kf, qf[c], st);
        }
#pragma unroll
        for (int r = 0; r < 4; ++r) pf[kt2 * 4 + r] = st[r];
      }
      __builtin_amdgcn_s_setprio(0);

      if (s == qtg) {  // diagonal causal mask
        const int qrel = 16 * kt2q + q15;
#pragma unroll
        for (int kt2 = 0; kt2 < 4; ++kt2)
#pragma unroll
          for (int r = 0; r < 4; ++r)
            if (kt2 * 16 + g * 4 + r > qrel) pf[kt2 * 4 + r] = -1e30f;
      }

      // online softmax, defer-max fast path
      float m0 = fmaxf(fmaxf(pf[0], pf[1]), fmaxf(pf[2], pf[3]));
      float m1 = fmaxf(fmaxf(pf[4], pf[5]), fmaxf(pf[6], pf[7]));
      float m2 = fmaxf(fmaxf(pf[8], pf[9]), fmaxf(pf[10], pf[11]));
      float m3 = fmaxf(fmaxf(pf[12], pf[13]), fmaxf(pf[14], pf[15]));
      float tmax = fmaxf(fmaxf(m0, m1), fmaxf(m2, m3));
      tmax = fmaxf(tmax, __shfl_xor(tmax, 16));
      tmax = fmaxf(tmax, __shfl_xor(tmax, 32));

      if (__all(tmax <= mrun)) {
        const float nmc = -mrun * SCALE_LOG2E;
#pragma unroll
        for (int i = 0; i < 16; ++i) pf[i] = exp2f(fmaf(pf[i], SCALE_LOG2E, nmc));
      } else {
        const float mnew = fmaxf(mrun, tmax);
        const float al = exp2f((mrun - mnew) * SCALE_LOG2E);
        mrun = mnew;
        const float nmc = -mnew * SCALE_LOG2E;
#pragma unroll
        for (int i = 0; i < 16; ++i) pf[i] = exp2f(fmaf(pf[i], SCALE_LOG2E, nmc));
        lrun *= al;
        float ar[4];
#pragma unroll
        for (int r = 0; r < 4; ++r) ar[r] = __shfl(al, g * 4 + r);
#pragma unroll
        for (int dt = 0; dt < 8; ++dt)
#pragma unroll
          for (int r = 0; r < 4; ++r) acc[dt][r] *= ar[r];
      }
      {
        float s01 = (pf[0] + pf[1]) + (pf[2] + pf[3]);
        float s23 = (pf[4] + pf[5]) + (pf[6] + pf[7]);
        float s45 = (pf[8] + pf[9]) + (pf[10] + pf[11]);
        float s67 = (pf[12] + pf[13]) + (pf[14] + pf[15]);
        lrun += (s01 + s23) + (s45 + s67);
      }

      // P -> per-wave LDS as [k-octet m][q15] 16B units (conflict-free read)
      {
        const int wb = q15 * 16 + (g & 1) * 8;
#pragma unroll
        for (int kt2 = 0; kt2 < 4; ++kt2) {
          u16x4 o = {f2bf(pf[kt2 * 4]), f2bf(pf[kt2 * 4 + 1]),
                     f2bf(pf[kt2 * 4 + 2]), f2bf(pf[kt2 * 4 + 3])};
          *(u16x4*)(plw + (kt2 * 2 + (g >> 1)) * 256 + wb) = o;
        }
      }
      asm volatile("s_waitcnt lgkmcnt(0)" ::: "memory");
    }

    if (s > 0) {  // kvt(s) ready; leave kv(s+1):2 outstanding if staged
      if (s + 1 < nsteps) asm volatile("s_waitcnt vmcnt(2)" ::: "memory");
      else                asm volatile("s_waitcnt vmcnt(0)" ::: "memory");
      __builtin_amdgcn_s_barrier();
      asm volatile("" ::: "memory");
    }

    if (active) {
      // PV: acc[dt] += P(16x64) * V(64x16 slice dt); all reads linear
      bf16x8 pa0 = *(const bf16x8*)(plw + g * 256 + q15 * 16);
      bf16x8 pa1 = *(const bf16x8*)(plw + (4 + g) * 256 + q15 * 16);
      __builtin_amdgcn_s_setprio(1);
#pragma unroll
      for (int dt = 0; dt < 8; ++dt) {
        bf16x8 vb0 = *(const bf16x8*)(kvtb + dt * 1024 + l16);
        bf16x8 vb1 = *(const bf16x8*)(kvtb + (8 + dt) * 1024 + l16);
        acc[dt] = mfma16(pa0, vb0, acc[dt]);
        acc[dt] = mfma16(pa1, vb1, acc[dt]);
      }
      __builtin_amdgcn_s_setprio(0);
    }

    if (s == qtg) {  // this wave-group is done: normalize and write out
      lrun += __shfl_xor(lrun, 16);
      lrun += __shfl_xor(lrun, 32);
      const float inv = 1.f / lrun;
      float ir[4];
#pragma unroll
      for (int r = 0; r < 4; ++r) ir[r] = __shfl(inv, g * 4 + r);
      float* ob = out + ((size_t)b * TL + qtg * 64 + 16 * kt2q) * TE + h * TD;
#pragma unroll
      for (int dt = 0; dt < 8; ++dt)
#pragma unroll
        for (int r = 0; r < 4; ++r)
          ob[(g * 4 + r) * TE + dt * 16 + q15] = acc[dt][r] * ir[r];
    }

    // all waves done reading kv(s)/kvt(s); refill
    __builtin_amdgcn_s_barrier();
    asm volatile("" ::: "memory");
    if (s + 1 < nsteps) STAGE_KVT(s + 1);
    if (s + 2 < nsteps) STAGE_KV(s & 1, s + 2);
  }
}

// ---------------- fallback (v1-style, self-contained, no ws needed) ---------
__device__ __forceinline__ bf16x8 ld256s(const unsigned short* base, int row, int inrow) {
  const int off = (row * 256 + inrow) ^ ((row & 7) << 4);
  return *(const bf16x8*)((const char*)base + off);
}
__device__ __forceinline__ bf16x8 ld128s(const unsigned short* base, int row, int inrow) {
  const int off = (row * 128 + inrow) ^ ((row & 7) << 4);
  return *(const bf16x8*)((const char*)base + off);
}

__device__ __forceinline__ void stage_tile_fb(const float* __restrict__ src,
                                              unsigned short* kv, unsigned short* kvt,
                                              int t) {
  const int kr = (t >> 4) << 2;
  const int d0 = (t & 15) << 3;
  unsigned short c[4][8];
#pragma unroll
  for (int rr = 0; rr < 4; ++rr) {
    const float* p = src + (kr + rr) * TE + d0;
    const float4 a = *(const float4*)p;
    const float4 b = *(const float4*)(p + 4);
    c[rr][0] = f2bf(a.x); c[rr][1] = f2bf(a.y); c[rr][2] = f2bf(a.z); c[rr][3] = f2bf(a.w);
    c[rr][4] = f2bf(b.x); c[rr][5] = f2bf(b.y); c[rr][6] = f2bf(b.z); c[rr][7] = f2bf(b.w);
  }
#pragma unroll
  for (int rr = 0; rr < 4; ++rr) {
    const int r = kr + rr;
    u16x8 o = {c[rr][0], c[rr][1], c[rr][2], c[rr][3],
               c[rr][4], c[rr][5], c[rr][6], c[rr][7]};
    const int off = (r * 256 + d0 * 2) ^ ((r & 7) << 4);
    *(u16x8*)((char*)kv + off) = o;
  }
#pragma unroll
  for (int cc = 0; cc < 8; ++cc) {
    const int d = d0 + cc;
    u16x4 o = {c[0][cc], c[1][cc], c[2][cc], c[3][cc]};
    const int off = (d * 128 + kr * 2) ^ ((d & 7) << 4);
    *(u16x4*)((char*)kvt + off) = o;
  }
}

__global__ void __launch_bounds__(256)
evo_attn(const float* __restrict__ x, float* __restrict__ out) {
  __shared__ unsigned short kv[KB * TD];
  __shared__ unsigned short kvt[TD * KB];
  __shared__ unsigned short pl[4 * 16 * KB];

  const int t = threadIdx.x;
  const int lane = t & 63;
  const int w = t >> 6;
  const int g = lane >> 4;
  const int q15 = lane & 15;

  const int bh = blockIdx.x & 31;
  const int qt = 31 - (blockIdx.x >> 5);
  const int b = bh >> 4;
  const int h = bh & 15;
  const float* xb = x + (size_t)b * TL * TE + h * TD;
  const int q0 = qt * KB;

  stage_tile_fb(xb + (size_t)q0 * TE, kv, kvt, t);
  __syncthreads();

  bf16x8 qf[4];
#pragma unroll
  for (int c = 0; c < 4; ++c)
    qf[c] = ld256s(kv, 16 * w + q15, c * 64 + g * 16);

  f32x4 acc[8];
#pragma unroll
  for (int dt = 0; dt < 8; ++dt) acc[dt] = (f32x4){0.f, 0.f, 0.f, 0.f};
  float mrun = -1e30f;
  float lrun = 0.f;
  unsigned short* plw = pl + w * (16 * KB);

  for (int s = 0; s <= qt; ++s) {
    if (s > 0) {
      __syncthreads();
      stage_tile_fb(xb + (size_t)(s - 1) * KB * TE, kv, kvt, t);
      __syncthreads();
    }
    float sv[16];
#pragma unroll
    for (int kt2 = 0; kt2 < 4; ++kt2) {
      f32x4 st = (f32x4){0.f, 0.f, 0.f, 0.f};
#pragma unroll
      for (int c = 0; c < 4; ++c) {
        bf16x8 kf = ld256s(kv, kt2 * 16 + q15, c * 64 + g * 16);
        st = mfma16(kf, qf[c], st);
      }
#pragma unroll
      for (int r = 0; r < 4; ++r) sv[kt2 * 4 + r] = st[r] * SCALE_LOG2E;
    }
    if (s == 0) {
      const int qrel = 16 * w + q15;
#pragma unroll
      for (int kt2 = 0; kt2 < 4; ++kt2)
#pragma unroll
        for (int r = 0; r < 4; ++r)
          if (kt2 * 16 + g * 4 + r > qrel) sv[kt2 * 4 + r] = -1e30f;
    }
    float tmax = sv[0];
#pragma unroll
    for (int i = 1; i < 16; ++i) tmax = fmaxf(tmax, sv[i]);
    tmax = fmaxf(tmax, __shfl_xor(tmax, 16));
    tmax = fmaxf(tmax, __shfl_xor(tmax, 32));
    const float mnew = fmaxf(mrun, tmax);
    const float al = exp2f(mrun - mnew);
    mrun = mnew;
    float psum = 0.f;
    unsigned short pb[16];
#pragma unroll
    for (int i = 0; i < 16; ++i) {
      const float p = exp2f(sv[i] - mnew);
      psum += p;
      pb[i] = f2bf(p);
    }
    lrun = lrun * al + psum;
#pragma unroll
    for (int kt2 = 0; kt2 < 4; ++kt2) {
      u16x4 o = {pb[kt2 * 4], pb[kt2 * 4 + 1], pb[kt2 * 4 + 2], pb[kt2 * 4 + 3]};
      const int off = (q15 * 128 + kt2 * 32 + g * 8) ^ ((q15 & 7) << 4);
      *(u16x4*)((char*)plw + off) = o;
    }
    asm volatile("s_waitcnt lgkmcnt(0)" ::: "memory");
    float ar[4];
#pragma unroll
    for (int r = 0; r < 4; ++r) ar[r] = __shfl(al, g * 4 + r);
#pragma unroll
    for (int dt = 0; dt < 8; ++dt)
#pragma unroll
      for (int r = 0; r < 4; ++r) acc[dt][r] *= ar[r];
    bf16x8 pa0 = ld128s(plw, q15, g * 16);
    bf16x8 pa1 = ld128s(plw, q15, 64 + g * 16);
#pragma unroll
    for (int dt = 0; dt < 8; ++dt) {
      bf16x8 vb0 = ld128s(kvt, dt * 16 + q15, g * 16);
      bf16x8 vb1 = ld128s(kvt, dt * 16 + q15, 64 + g * 16);
      acc[dt] = mfma16(pa0, vb0, acc[dt]);
      acc[dt] = mfma16(pa1, vb1, acc[dt]);
    }
  }

  lrun += __shfl_xor(lrun, 16);
  lrun += __shfl_xor(lrun, 32);
  const float inv = 1.f / lrun;
  float ir[4];
#pragma unroll
  for (int r = 0; r < 4; ++r) ir[r] = __shfl(inv, g * 4 + r);
  float* ob = out + ((size_t)b * TL + q0 + 16 * w) * TE + h * TD;
#pragma unroll
  for (int dt = 0; dt < 8; ++dt)
#pragma unroll
    for (int r = 0; r < 4; ++r)
      ob[(g * 4 + r) * TE + dt * 16 + q15] = acc[dt][r] * ir[r];
}

extern "C" void kernel_launch(void* const* d_in, const int* in_sizes, int n_in,
                              void* d_out, int out_size, void* d_ws, size_t ws_size,
                              hipStream_t stream) {
  const float* x = (const float*)d_in[0];
  float* out = (float*)d_out;
  (void)in_sizes; (void)n_in; (void)out_size;
  if (ws_size >= (size_t)WS_NEED) {
    char* wsb = (char*)d_ws;
    prepack<<<dim3(1024), dim3(256), 0, stream>>>(x, wsb);
    evo_attn7<<<dim3(512), dim3(512), 0, stream>>>(wsb, out);
  } else {
    evo_attn<<<dim3(1024), dim3(256), 0, stream>>>(x, out);
  }
}

// Round 15
// 92.452 us; speedup vs baseline: 1.6696x; 1.6696x over previous
//
#include <hip/hip_runtime.h>
#include <hip/hip_bf16.h>

// EvoAttn: causal self-attention with Q=K=V = x.reshape(B,L,H,D).
// B=2 H=16 L=2048 D=128, fp32 in/out, bf16 MFMA compute.
// v15 = v9 (best: 80us) with kvt double-buffered -> ONE barrier + one
//       already-satisfied vmcnt(0) per step (was 3 barriers + 2 waits).
//       LDS 72KB, still 2 blocks/CU. Everything else identical to v9.

#define TL 2048
#define TE 2048
#define TD 128
#define KB 64
#define NTILES 32                          // TL / KB
#define TILE_B 16384                       // 64*128*2 bytes
#define KV_REGION (32 * NTILES * TILE_B)   // 16 MB per layout
#define WS_NEED (2u * (unsigned)KV_REGION) // 32 MB

typedef __attribute__((ext_vector_type(8))) short bf16x8;
typedef __attribute__((ext_vector_type(4))) float f32x4;
typedef __attribute__((ext_vector_type(8))) unsigned short u16x8;
typedef __attribute__((ext_vector_type(4))) unsigned short u16x4;

// (1/sqrt(128)) * log2(e)
#define SCALE_LOG2E 0.12751879f

__device__ __forceinline__ unsigned short f2bf(float f) {
  __hip_bfloat16 h = __float2bfloat16(f);
  return __builtin_bit_cast(unsigned short, h);
}

__device__ __forceinline__ f32x4 mfma16(bf16x8 a, bf16x8 b, f32x4 c) {
  return __builtin_amdgcn_mfma_f32_16x16x32_bf16(a, b, c, 0, 0, 0);
}

__device__ __forceinline__ void gl_lds16(const void* g, void* l) {
  __builtin_amdgcn_global_load_lds(
      (__attribute__((address_space(1))) void*)(g),
      (__attribute__((address_space(3))) void*)(l), 16, 0, 0);
}

// ws layout (per tile bid = bh*32 + kt):
// K region: 16B frag (kt2,c,g,q15) at ((kt2*4+c)*64 + g*16 + q15)*16
//   holding K[kt2*16+q15][c*32+g*8 .. +8).
// V region: 16B frag (half,dt,g,q15) at ((half*8+dt)*64 + g*16 + q15)*16
//   holding V[k=half*32+g*8+j][d=dt*16+q15].
__global__ void __launch_bounds__(256)
prepack(const float* __restrict__ x, char* __restrict__ wsb) {
  const int bid = blockIdx.x;            // bh*32 + kt
  const int kt = bid & 31;
  const int bh = bid >> 5;
  const int b = bh >> 4;
  const int h = bh & 15;
  const float* src = x + (size_t)b * TL * TE + h * TD + (size_t)kt * KB * TE;
  const int t = threadIdx.x;
  const int kr = (t >> 4) << 2;          // 4 consecutive k-rows
  const int d0 = (t & 15) << 3;          // 8 d-cols
  unsigned short c[4][8];
#pragma unroll
  for (int rr = 0; rr < 4; ++rr) {
    const float* p = src + (kr + rr) * TE + d0;
    const float4 a = *(const float4*)p;
    const float4 bb = *(const float4*)(p + 4);
    c[rr][0] = f2bf(a.x);  c[rr][1] = f2bf(a.y);  c[rr][2] = f2bf(a.z);  c[rr][3] = f2bf(a.w);
    c[rr][4] = f2bf(bb.x); c[rr][5] = f2bf(bb.y); c[rr][6] = f2bf(bb.z); c[rr][7] = f2bf(bb.w);
  }
  // K fragment order
  char* gkv = wsb + (size_t)bid * TILE_B;
  const int kt2 = kr >> 4;
  const int q0r = kr & 15;
  const int cc_ = (t & 15) >> 2;
  const int gg_ = (t & 15) & 3;
#pragma unroll
  for (int rr = 0; rr < 4; ++rr) {
    u16x8 o = {c[rr][0], c[rr][1], c[rr][2], c[rr][3],
               c[rr][4], c[rr][5], c[rr][6], c[rr][7]};
    const int off = (((kt2 * 4 + cc_) * 64 + gg_ * 16 + (q0r + rr)) << 4);
    *(u16x8*)(gkv + off) = o;
  }
  // V fragment order
  char* gkt = wsb + KV_REGION + (size_t)bid * TILE_B;
  const int half = kr >> 5;
  const int g = (kr >> 3) & 3;
  const int j0 = kr & 7;                 // 0 or 4
#pragma unroll
  for (int cc = 0; cc < 8; ++cc) {
    const int d = d0 + cc;
    u16x4 o = {c[0][cc], c[1][cc], c[2][cc], c[3][cc]};   // k = kr..kr+3
    const int off = (((half * 8 + (d >> 4)) * 64 + g * 16 + (d & 15)) << 4) + j0 * 2;
    *(u16x4*)(gkt + off) = o;
  }
}

// ---------------- main attention kernel: pair (a, 31-a), 33 steps/block -----
__global__ void __launch_bounds__(256)
evo_attn8(const char* __restrict__ wsb, float* __restrict__ out) {
  // kv0 | kv1 | kvt0 | kvt1 | pl(4 waves x 2KB) = 72 KB -> 2 blocks/CU
  __shared__ char smem[4 * TILE_B + 8192];

  const int t = threadIdx.x;
  const int lane = t & 63;
  const int w = t >> 6;        // wave 0..3, owns q rows [q0+16w, q0+16w+16)
  const int g = lane >> 4;
  const int q15 = lane & 15;

  const int blk = blockIdx.x;            // 512 blocks
  const int bh = (blk & 7) * 4 + (blk >> 7);   // XCD-affine
  const int a = (blk >> 3) & 15;         // pair: q-tiles a and 31-a
  const int b = bh >> 4;
  const int h = bh & 15;

  const char* gkv = wsb + (size_t)bh * (NTILES * TILE_B);
  const char* gkt = wsb + KV_REGION + (size_t)bh * (NTILES * TILE_B);
  char* plw = smem + 4 * TILE_B + w * 2048;
  const int l16 = lane * 16;

#define STAGE_KV(BUFI, KT)                                                 \
  {                                                                        \
    char* dst_ = smem + (BUFI) * TILE_B + (t >> 6) * 1024;                 \
    const char* src_ = gkv + (size_t)(KT) * TILE_B + t * 16;               \
    _Pragma("unroll")                                                      \
    for (int i_ = 0; i_ < 4; ++i_) gl_lds16(src_ + i_ * 4096, dst_ + i_ * 4096); \
  }
#define STAGE_KVT(BUFI, KT)                                                \
  {                                                                        \
    char* dst_ = smem + (2 + (BUFI)) * TILE_B + (t >> 6) * 1024;           \
    const char* src_ = gkt + (size_t)(KT) * TILE_B + t * 16;               \
    _Pragma("unroll")                                                      \
    for (int i_ = 0; i_ < 4; ++i_) gl_lds16(src_ + i_ * 4096, dst_ + i_ * 4096); \
  }

  // tile index for step s of segment qt: s=0 -> diag(qt), s>0 -> s-1
#define TIDX(S) (((S) == 0) ? qt : ((S)-1))

#pragma unroll 1
  for (int seg = 0; seg < 2; ++seg) {
    const int qt = seg ? (31 - a) : a;   // q-tile (64 rows at 64*qt)
    const int nt = qt + 1;

    // prologue: stage tiles for s=0 (diag) and s=1
    STAGE_KV(0, qt);
    STAGE_KVT(0, qt);
    if (nt > 1) { STAGE_KV(1, 0); STAGE_KVT(1, 0); }
    if (nt > 1) asm volatile("s_waitcnt vmcnt(8)" ::: "memory");
    else        asm volatile("s_waitcnt vmcnt(0)" ::: "memory");
    __builtin_amdgcn_s_barrier();
    asm volatile("" ::: "memory");

    // Q fragments from kv buf0 (diag tile IS the Q tile); kt2 = w
    bf16x8 qf[4];
#pragma unroll
    for (int c = 0; c < 4; ++c)
      qf[c] = *(const bf16x8*)(smem + (w * 4 + c) * 1024 + l16);

    f32x4 acc[8];
#pragma unroll
    for (int dt = 0; dt < 8; ++dt) acc[dt] = (f32x4){0.f, 0.f, 0.f, 0.f};
    float mrun = -1e30f;   // raw score domain
    float lrun = 0.f;

    for (int s = 0; s < nt; ++s) {
      const char* kv = smem + (s & 1) * TILE_B;
      const char* kvtb = smem + (2 + (s & 1)) * TILE_B;

      // QK^T: lane (g,q15) holds S[k=kt2*16+g*4+r][q=16w+q15] (raw)
      float pf[16];
      __builtin_amdgcn_s_setprio(1);
#pragma unroll
      for (int kt2 = 0; kt2 < 4; ++kt2) {
        f32x4 st = (f32x4){0.f, 0.f, 0.f, 0.f};
#pragma unroll
        for (int c = 0; c < 4; ++c) {
          bf16x8 kf = *(const bf16x8*)(kv + (kt2 * 4 + c) * 1024 + l16);
          st = mfma16(kf, qf[c], st);
        }
#pragma unroll
        for (int r = 0; r < 4; ++r) pf[kt2 * 4 + r] = st[r];
      }
      __builtin_amdgcn_s_setprio(0);

      if (s == 0) {  // diagonal causal mask
        const int qrel = 16 * w + q15;
#pragma unroll
        for (int kt2 = 0; kt2 < 4; ++kt2)
#pragma unroll
          for (int r = 0; r < 4; ++r)
            if (kt2 * 16 + g * 4 + r > qrel) pf[kt2 * 4 + r] = -1e30f;
      }

      // online softmax, defer-max fast path
      float m0 = fmaxf(fmaxf(pf[0], pf[1]), fmaxf(pf[2], pf[3]));
      float m1 = fmaxf(fmaxf(pf[4], pf[5]), fmaxf(pf[6], pf[7]));
      float m2 = fmaxf(fmaxf(pf[8], pf[9]), fmaxf(pf[10], pf[11]));
      float m3 = fmaxf(fmaxf(pf[12], pf[13]), fmaxf(pf[14], pf[15]));
      float tmax = fmaxf(fmaxf(m0, m1), fmaxf(m2, m3));
      tmax = fmaxf(tmax, __shfl_xor(tmax, 16));
      tmax = fmaxf(tmax, __shfl_xor(tmax, 32));

      if (__all(tmax <= mrun)) {
        const float nmc = -mrun * SCALE_LOG2E;
#pragma unroll
        for (int i = 0; i < 16; ++i) pf[i] = exp2f(fmaf(pf[i], SCALE_LOG2E, nmc));
      } else {
        const float mnew = fmaxf(mrun, tmax);
        const float al = exp2f((mrun - mnew) * SCALE_LOG2E);
        mrun = mnew;
        const float nmc = -mnew * SCALE_LOG2E;
#pragma unroll
        for (int i = 0; i < 16; ++i) pf[i] = exp2f(fmaf(pf[i], SCALE_LOG2E, nmc));
        lrun *= al;
        float ar[4];
#pragma unroll
        for (int r = 0; r < 4; ++r) ar[r] = __shfl(al, g * 4 + r);
#pragma unroll
        for (int dt = 0; dt < 8; ++dt)
#pragma unroll
          for (int r = 0; r < 4; ++r) acc[dt][r] *= ar[r];
      }
      {
        float s01 = (pf[0] + pf[1]) + (pf[2] + pf[3]);
        float s23 = (pf[4] + pf[5]) + (pf[6] + pf[7]);
        float s45 = (pf[8] + pf[9]) + (pf[10] + pf[11]);
        float s67 = (pf[12] + pf[13]) + (pf[14] + pf[15]);
        lrun += (s01 + s23) + (s45 + s67);
      }

      // P -> per-wave LDS as [k-octet m][q15] 16B units (conflict-free read)
      {
        const int wb = q15 * 16 + (g & 1) * 8;
#pragma unroll
        for (int kt2 = 0; kt2 < 4; ++kt2) {
          u16x4 o = {f2bf(pf[kt2 * 4]), f2bf(pf[kt2 * 4 + 1]),
                     f2bf(pf[kt2 * 4 + 2]), f2bf(pf[kt2 * 4 + 3])};
          *(u16x4*)(plw + (kt2 * 2 + (g >> 1)) * 256 + wb) = o;
        }
      }
      asm volatile("s_waitcnt lgkmcnt(0)" ::: "memory");

      // PV: acc[dt] += P(16x64) * V(64x16 slice dt); all reads linear
      bf16x8 pa0 = *(const bf16x8*)(plw + g * 256 + q15 * 16);
      bf16x8 pa1 = *(const bf16x8*)(plw + (4 + g) * 256 + q15 * 16);
      __builtin_amdgcn_s_setprio(1);
#pragma unroll
      for (int dt = 0; dt < 8; ++dt) {
        bf16x8 vb0 = *(const bf16x8*)(kvtb + dt * 1024 + l16);
        bf16x8 vb1 = *(const bf16x8*)(kvtb + (8 + dt) * 1024 + l16);
        acc[dt] = mfma16(pa0, vb0, acc[dt]);
        acc[dt] = mfma16(pa1, vb1, acc[dt]);
      }
      __builtin_amdgcn_s_setprio(0);

      // tile(s+1) loads (issued a full step ago) must be done; then one
      // barrier: (a) everyone finished reading tile s -> its buffers are
      // reusable, (b) everyone's waits done -> tile s+1 readable by all.
      if (s + 1 < nt) asm volatile("s_waitcnt vmcnt(0)" ::: "memory");
      __builtin_amdgcn_s_barrier();
      asm volatile("" ::: "memory");
      if (s + 2 < nt) {   // refill the buffers tile s occupied
        STAGE_KV(s & 1, s + 1);     // TIDX(s+2) = s+1
        STAGE_KVT(s & 1, s + 1);
      }
    }

    // combine g-group partial sums, normalize, write out
    lrun += __shfl_xor(lrun, 16);
    lrun += __shfl_xor(lrun, 32);
    const float inv = 1.f / lrun;
    float ir[4];
#pragma unroll
    for (int r = 0; r < 4; ++r) ir[r] = __shfl(inv, g * 4 + r);

    float* ob = out + ((size_t)b * TL + qt * 64 + 16 * w) * TE + h * TD;
#pragma unroll
    for (int dt = 0; dt < 8; ++dt)
#pragma unroll
      for (int r = 0; r < 4; ++r)
        ob[(g * 4 + r) * TE + dt * 16 + q15] = acc[dt][r] * ir[r];
    // next segment's prologue stages are safe: all waves passed the final
    // step barrier (no LDS access in this epilogue).
  }
}

// ---------------- fallback (v1-style, self-contained, no ws needed) ---------
__device__ __forceinline__ bf16x8 ld256s(const unsigned short* base, int row, int inrow) {
  const int off = (row * 256 + inrow) ^ ((row & 7) << 4);
  return *(const bf16x8*)((const char*)base + off);
}
__device__ __forceinline__ bf16x8 ld128s(const unsigned short* base, int row, int inrow) {
  const int off = (row * 128 + inrow) ^ ((row & 7) << 4);
  return *(const bf16x8*)((const char*)base + off);
}

__device__ __forceinline__ void stage_tile_fb(const float* __restrict__ src,
                                              unsigned short* kv, unsigned short* kvt,
                                              int t) {
  const int kr = (t >> 4) << 2;
  const int d0 = (t & 15) << 3;
  unsigned short c[4][8];
#pragma unroll
  for (int rr = 0; rr < 4; ++rr) {
    const float* p = src + (kr + rr) * TE + d0;
    const float4 a = *(const float4*)p;
    const float4 b = *(const float4*)(p + 4);
    c[rr][0] = f2bf(a.x); c[rr][1] = f2bf(a.y); c[rr][2] = f2bf(a.z); c[rr][3] = f2bf(a.w);
    c[rr][4] = f2bf(b.x); c[rr][5] = f2bf(b.y); c[rr][6] = f2bf(b.z); c[rr][7] = f2bf(b.w);
  }
#pragma unroll
  for (int rr = 0; rr < 4; ++rr) {
    const int r = kr + rr;
    u16x8 o = {c[rr][0], c[rr][1], c[rr][2], c[rr][3],
               c[rr][4], c[rr][5], c[rr][6], c[rr][7]};
    const int off = (r * 256 + d0 * 2) ^ ((r & 7) << 4);
    *(u16x8*)((char*)kv + off) = o;
  }
#pragma unroll
  for (int cc = 0; cc < 8; ++cc) {
    const int d = d0 + cc;
    u16x4 o = {c[0][cc], c[1][cc], c[2][cc], c[3][cc]};
    const int off = (d * 128 + kr * 2) ^ ((d & 7) << 4);
    *(u16x4*)((char*)kvt + off) = o;
  }
}

__global__ void __launch_bounds__(256)
evo_attn(const float* __restrict__ x, float* __restrict__ out) {
  __shared__ unsigned short kv[KB * TD];
  __shared__ unsigned short kvt[TD * KB];
  __shared__ unsigned short pl[4 * 16 * KB];

  const int t = threadIdx.x;
  const int lane = t & 63;
  const int w = t >> 6;
  const int g = lane >> 4;
  const int q15 = lane & 15;

  const int bh = blockIdx.x & 31;
  const int qt = 31 - (blockIdx.x >> 5);
  const int b = bh >> 4;
  const int h = bh & 15;
  const float* xb = x + (size_t)b * TL * TE + h * TD;
  const int q0 = qt * KB;

  stage_tile_fb(xb + (size_t)q0 * TE, kv, kvt, t);
  __syncthreads();

  bf16x8 qf[4];
#pragma unroll
  for (int c = 0; c < 4; ++c)
    qf[c] = ld256s(kv, 16 * w + q15, c * 64 + g * 16);

  f32x4 acc[8];
#pragma unroll
  for (int dt = 0; dt < 8; ++dt) acc[dt] = (f32x4){0.f, 0.f, 0.f, 0.f};
  float mrun = -1e30f;
  float lrun = 0.f;
  unsigned short* plw = pl + w * (16 * KB);

  for (int s = 0; s <= qt; ++s) {
    if (s > 0) {
      __syncthreads();
      stage_tile_fb(xb + (size_t)(s - 1) * KB * TE, kv, kvt, t);
      __syncthreads();
    }
    float sv[16];
#pragma unroll
    for (int kt2 = 0; kt2 < 4; ++kt2) {
      f32x4 st = (f32x4){0.f, 0.f, 0.f, 0.f};
#pragma unroll
      for (int c = 0; c < 4; ++c) {
        bf16x8 kf = ld256s(kv, kt2 * 16 + q15, c * 64 + g * 16);
        st = mfma16(kf, qf[c], st);
      }
#pragma unroll
      for (int r = 0; r < 4; ++r) sv[kt2 * 4 + r] = st[r] * SCALE_LOG2E;
    }
    if (s == 0) {
      const int qrel = 16 * w + q15;
#pragma unroll
      for (int kt2 = 0; kt2 < 4; ++kt2)
#pragma unroll
        for (int r = 0; r < 4; ++r)
          if (kt2 * 16 + g * 4 + r > qrel) sv[kt2 * 4 + r] = -1e30f;
    }
    float tmax = sv[0];
#pragma unroll
    for (int i = 1; i < 16; ++i) tmax = fmaxf(tmax, sv[i]);
    tmax = fmaxf(tmax, __shfl_xor(tmax, 16));
    tmax = fmaxf(tmax, __shfl_xor(tmax, 32));
    const float mnew = fmaxf(mrun, tmax);
    const float al = exp2f(mrun - mnew);
    mrun = mnew;
    float psum = 0.f;
    unsigned short pb[16];
#pragma unroll
    for (int i = 0; i < 16; ++i) {
      const float p = exp2f(sv[i] - mnew);
      psum += p;
      pb[i] = f2bf(p);
    }
    lrun = lrun * al + psum;
#pragma unroll
    for (int kt2 = 0; kt2 < 4; ++kt2) {
      u16x4 o = {pb[kt2 * 4], pb[kt2 * 4 + 1], pb[kt2 * 4 + 2], pb[kt2 * 4 + 3]};
      const int off = (q15 * 128 + kt2 * 32 + g * 8) ^ ((q15 & 7) << 4);
      *(u16x4*)((char*)plw + off) = o;
    }
    asm volatile("s_waitcnt lgkmcnt(0)" ::: "memory");
    float ar[4];
#pragma unroll
    for (int r = 0; r < 4; ++r) ar[r] = __shfl(al, g * 4 + r);
#pragma unroll
    for (int dt = 0; dt < 8; ++dt)
#pragma unroll
      for (int r = 0; r < 4; ++r) acc[dt][r] *= ar[r];
    bf16x8 pa0 = ld128s(plw, q15, g * 16);
    bf16x8 pa1 = ld128s(plw, q15, 64 + g * 16);
#pragma unroll
    for (int dt = 0; dt < 8; ++dt) {
      bf16x8 vb0 = ld128s(kvt, dt * 16 + q15, g * 16);
      bf16x8 vb1 = ld128s(kvt, dt * 16 + q15, 64 + g * 16);
      acc[dt] = mfma16(pa0, vb0, acc[dt]);
      acc[dt] = mfma16(pa1, vb1, acc[dt]);
    }
  }

  lrun += __shfl_xor(lrun, 16);
  lrun += __shfl_xor(lrun, 32);
  const float inv = 1.f / lrun;
  float ir[4];
#pragma unroll
  for (int r = 0; r < 4; ++r) ir[r] = __shfl(inv, g * 4 + r);
  float* ob = out + ((size_t)b * TL + q0 + 16 * w) * TE + h * TD;
#pragma unroll
  for (int dt = 0; dt < 8; ++dt)
#pragma unroll
    for (int r = 0; r < 4; ++r)
      ob[(g * 4 + r) * TE + dt * 16 + q15] = acc[dt][r] * ir[r];
}

extern "C" void kernel_launch(void* const* d_in, const int* in_sizes, int n_in,
                              void* d_out, int out_size, void* d_ws, size_t ws_size,
                              hipStream_t stream) {
  const float* x = (const float*)d_in[0];
  float* out = (float*)d_out;
  (void)in_sizes; (void)n_in; (void)out_size;
  if (ws_size >= (size_t)WS_NEED) {
    char* wsb = (char*)d_ws;
    prepack<<<dim3(1024), dim3(256), 0, stream>>>(x, wsb);
    evo_attn8<<<dim3(512), dim3(256), 0, stream>>>(wsb, out);
  } else {
    evo_attn<<<dim3(1024), dim3(256), 0, stream>>>(x, out);
  }
}

// Round 16
// 89.173 us; speedup vs baseline: 1.7310x; 1.0368x over previous
//
#include <hip/hip_runtime.h>
#include <hip/hip_bf16.h>

// EvoAttn: causal self-attention with Q=K=V = x.reshape(B,L,H,D).
// B=2 H=16 L=2048 D=128, fp32 in/out, bf16 MFMA compute.
// v16 = v15 main kernel (78us, best) + LDS-mediated prepack (v8-style):
//       fragment-order images built in LDS, then coalesced 64B copy-out.

#define TL 2048
#define TE 2048
#define TD 128
#define KB 64
#define NTILES 32                          // TL / KB
#define TILE_B 16384                       // 64*128*2 bytes
#define KV_REGION (32 * NTILES * TILE_B)   // 16 MB per layout
#define WS_NEED (2u * (unsigned)KV_REGION) // 32 MB

typedef __attribute__((ext_vector_type(8))) short bf16x8;
typedef __attribute__((ext_vector_type(4))) float f32x4;
typedef __attribute__((ext_vector_type(8))) unsigned short u16x8;
typedef __attribute__((ext_vector_type(4))) unsigned short u16x4;

// (1/sqrt(128)) * log2(e)
#define SCALE_LOG2E 0.12751879f

__device__ __forceinline__ unsigned short f2bf(float f) {
  __hip_bfloat16 h = __float2bfloat16(f);
  return __builtin_bit_cast(unsigned short, h);
}

__device__ __forceinline__ f32x4 mfma16(bf16x8 a, bf16x8 b, f32x4 c) {
  return __builtin_amdgcn_mfma_f32_16x16x32_bf16(a, b, c, 0, 0, 0);
}

__device__ __forceinline__ void gl_lds16(const void* g, void* l) {
  __builtin_amdgcn_global_load_lds(
      (__attribute__((address_space(1))) void*)(g),
      (__attribute__((address_space(3))) void*)(l), 16, 0, 0);
}

// ws layout (per tile bid = bh*32 + kt):
// K region: 16B frag (kt2,c,g,q15) at ((kt2*4+c)*64 + g*16 + q15)*16
//   holding K[kt2*16+q15][c*32+g*8 .. +8).
// V region: 16B frag (half,dt,g,q15) at ((half*8+dt)*64 + g*16 + q15)*16
//   holding V[k=half*32+g*8+j][d=dt*16+q15].
// Prepack: build both images in LDS (scattered small writes are cheap in
// LDS), then copy out with fully-coalesced 64B-per-thread stores.
__global__ void __launch_bounds__(256)
prepack(const float* __restrict__ x, char* __restrict__ wsb) {
  __shared__ unsigned short kimg[8192];   // 16 KB K-fragment image
  __shared__ unsigned short vimg[8192];   // 16 KB V-fragment image

  const int bid = blockIdx.x;            // bh*32 + kt
  const int kt = bid & 31;
  const int bh = bid >> 5;
  const int b = bh >> 4;
  const int h = bh & 15;
  const float* src = x + (size_t)b * TL * TE + h * TD + (size_t)kt * KB * TE;
  const int t = threadIdx.x;
  const int kr = (t >> 4) << 2;          // 4 consecutive k-rows
  const int d0 = (t & 15) << 3;          // 8 d-cols
  unsigned short c[4][8];
#pragma unroll
  for (int rr = 0; rr < 4; ++rr) {
    const float* p = src + (kr + rr) * TE + d0;
    const float4 a = *(const float4*)p;
    const float4 bb = *(const float4*)(p + 4);
    c[rr][0] = f2bf(a.x);  c[rr][1] = f2bf(a.y);  c[rr][2] = f2bf(a.z);  c[rr][3] = f2bf(a.w);
    c[rr][4] = f2bf(bb.x); c[rr][5] = f2bf(bb.y); c[rr][6] = f2bf(bb.z); c[rr][7] = f2bf(bb.w);
  }
  // K fragment image (LDS)
  const int kt2 = kr >> 4;
  const int q0r = kr & 15;
  const int cc_ = (t & 15) >> 2;
  const int gg_ = (t & 15) & 3;
#pragma unroll
  for (int rr = 0; rr < 4; ++rr) {
    u16x8 o = {c[rr][0], c[rr][1], c[rr][2], c[rr][3],
               c[rr][4], c[rr][5], c[rr][6], c[rr][7]};
    const int off = (((kt2 * 4 + cc_) * 64 + gg_ * 16 + (q0r + rr)) << 4);
    *(u16x8*)((char*)kimg + off) = o;
  }
  // V fragment image (LDS)
  const int half = kr >> 5;
  const int g = (kr >> 3) & 3;
  const int j0 = kr & 7;                 // 0 or 4
#pragma unroll
  for (int cc = 0; cc < 8; ++cc) {
    const int d = d0 + cc;
    u16x4 o = {c[0][cc], c[1][cc], c[2][cc], c[3][cc]};   // k = kr..kr+3
    const int off = (((half * 8 + (d >> 4)) * 64 + g * 16 + (d & 15)) << 4) + j0 * 2;
    *(u16x4*)((char*)vimg + off) = o;
  }
  __syncthreads();

  // coalesced copy-out: 64B per thread per image
  char* gkv = wsb + (size_t)bid * TILE_B;
  char* gkt = wsb + KV_REGION + (size_t)bid * TILE_B;
  const char* ki = (const char*)kimg;
  const char* vi = (const char*)vimg;
#pragma unroll
  for (int i = 0; i < 4; ++i) {
    *(u16x8*)(gkv + t * 64 + i * 16) = *(const u16x8*)(ki + t * 64 + i * 16);
    *(u16x8*)(gkt + t * 64 + i * 16) = *(const u16x8*)(vi + t * 64 + i * 16);
  }
}

// ---------------- main attention kernel: pair (a, 31-a), 33 steps/block -----
__global__ void __launch_bounds__(256)
evo_attn8(const char* __restrict__ wsb, float* __restrict__ out) {
  // kv0 | kv1 | kvt0 | kvt1 | pl(4 waves x 2KB) = 72 KB -> 2 blocks/CU
  __shared__ char smem[4 * TILE_B + 8192];

  const int t = threadIdx.x;
  const int lane = t & 63;
  const int w = t >> 6;        // wave 0..3, owns q rows [q0+16w, q0+16w+16)
  const int g = lane >> 4;
  const int q15 = lane & 15;

  const int blk = blockIdx.x;            // 512 blocks
  const int bh = (blk & 7) * 4 + (blk >> 7);   // XCD-affine
  const int a = (blk >> 3) & 15;         // pair: q-tiles a and 31-a
  const int b = bh >> 4;
  const int h = bh & 15;

  const char* gkv = wsb + (size_t)bh * (NTILES * TILE_B);
  const char* gkt = wsb + KV_REGION + (size_t)bh * (NTILES * TILE_B);
  char* plw = smem + 4 * TILE_B + w * 2048;
  const int l16 = lane * 16;

#define STAGE_KV(BUFI, KT)                                                 \
  {                                                                        \
    char* dst_ = smem + (BUFI) * TILE_B + (t >> 6) * 1024;                 \
    const char* src_ = gkv + (size_t)(KT) * TILE_B + t * 16;               \
    _Pragma("unroll")                                                      \
    for (int i_ = 0; i_ < 4; ++i_) gl_lds16(src_ + i_ * 4096, dst_ + i_ * 4096); \
  }
#define STAGE_KVT(BUFI, KT)                                                \
  {                                                                        \
    char* dst_ = smem + (2 + (BUFI)) * TILE_B + (t >> 6) * 1024;           \
    const char* src_ = gkt + (size_t)(KT) * TILE_B + t * 16;               \
    _Pragma("unroll")                                                      \
    for (int i_ = 0; i_ < 4; ++i_) gl_lds16(src_ + i_ * 4096, dst_ + i_ * 4096); \
  }

#pragma unroll 1
  for (int seg = 0; seg < 2; ++seg) {
    const int qt = seg ? (31 - a) : a;   // q-tile (64 rows at 64*qt)
    const int nt = qt + 1;

    // prologue: stage tiles for s=0 (diag) and s=1
    STAGE_KV(0, qt);
    STAGE_KVT(0, qt);
    if (nt > 1) { STAGE_KV(1, 0); STAGE_KVT(1, 0); }
    if (nt > 1) asm volatile("s_waitcnt vmcnt(8)" ::: "memory");
    else        asm volatile("s_waitcnt vmcnt(0)" ::: "memory");
    __builtin_amdgcn_s_barrier();
    asm volatile("" ::: "memory");

    // Q fragments from kv buf0 (diag tile IS the Q tile); kt2 = w
    bf16x8 qf[4];
#pragma unroll
    for (int c = 0; c < 4; ++c)
      qf[c] = *(const bf16x8*)(smem + (w * 4 + c) * 1024 + l16);

    f32x4 acc[8];
#pragma unroll
    for (int dt = 0; dt < 8; ++dt) acc[dt] = (f32x4){0.f, 0.f, 0.f, 0.f};
    float mrun = -1e30f;   // raw score domain
    float lrun = 0.f;

    for (int s = 0; s < nt; ++s) {
      const char* kv = smem + (s & 1) * TILE_B;
      const char* kvtb = smem + (2 + (s & 1)) * TILE_B;

      // QK^T: lane (g,q15) holds S[k=kt2*16+g*4+r][q=16w+q15] (raw)
      float pf[16];
      __builtin_amdgcn_s_setprio(1);
#pragma unroll
      for (int kt2 = 0; kt2 < 4; ++kt2) {
        f32x4 st = (f32x4){0.f, 0.f, 0.f, 0.f};
#pragma unroll
        for (int c = 0; c < 4; ++c) {
          bf16x8 kf = *(const bf16x8*)(kv + (kt2 * 4 + c) * 1024 + l16);
          st = mfma16(kf, qf[c], st);
        }
#pragma unroll
        for (int r = 0; r < 4; ++r) pf[kt2 * 4 + r] = st[r];
      }
      __builtin_amdgcn_s_setprio(0);

      if (s == 0) {  // diagonal causal mask
        const int qrel = 16 * w + q15;
#pragma unroll
        for (int kt2 = 0; kt2 < 4; ++kt2)
#pragma unroll
          for (int r = 0; r < 4; ++r)
            if (kt2 * 16 + g * 4 + r > qrel) pf[kt2 * 4 + r] = -1e30f;
      }

      // online softmax, defer-max fast path
      float m0 = fmaxf(fmaxf(pf[0], pf[1]), fmaxf(pf[2], pf[3]));
      float m1 = fmaxf(fmaxf(pf[4], pf[5]), fmaxf(pf[6], pf[7]));
      float m2 = fmaxf(fmaxf(pf[8], pf[9]), fmaxf(pf[10], pf[11]));
      float m3 = fmaxf(fmaxf(pf[12], pf[13]), fmaxf(pf[14], pf[15]));
      float tmax = fmaxf(fmaxf(m0, m1), fmaxf(m2, m3));
      tmax = fmaxf(tmax, __shfl_xor(tmax, 16));
      tmax = fmaxf(tmax, __shfl_xor(tmax, 32));

      if (__all(tmax <= mrun)) {
        const float nmc = -mrun * SCALE_LOG2E;
#pragma unroll
        for (int i = 0; i < 16; ++i) pf[i] = exp2f(fmaf(pf[i], SCALE_LOG2E, nmc));
      } else {
        const float mnew = fmaxf(mrun, tmax);
        const float al = exp2f((mrun - mnew) * SCALE_LOG2E);
        mrun = mnew;
        const float nmc = -mnew * SCALE_LOG2E;
#pragma unroll
        for (int i = 0; i < 16; ++i) pf[i] = exp2f(fmaf(pf[i], SCALE_LOG2E, nmc));
        lrun *= al;
        float ar[4];
#pragma unroll
        for (int r = 0; r < 4; ++r) ar[r] = __shfl(al, g * 4 + r);
#pragma unroll
        for (int dt = 0; dt < 8; ++dt)
#pragma unroll
          for (int r = 0; r < 4; ++r) acc[dt][r] *= ar[r];
      }
      {
        float s01 = (pf[0] + pf[1]) + (pf[2] + pf[3]);
        float s23 = (pf[4] + pf[5]) + (pf[6] + pf[7]);
        float s45 = (pf[8] + pf[9]) + (pf[10] + pf[11]);
        float s67 = (pf[12] + pf[13]) + (pf[14] + pf[15]);
        lrun += (s01 + s23) + (s45 + s67);
      }

      // P -> per-wave LDS as [k-octet m][q15] 16B units (conflict-free read)
      {
        const int wb = q15 * 16 + (g & 1) * 8;
#pragma unroll
        for (int kt2 = 0; kt2 < 4; ++kt2) {
          u16x4 o = {f2bf(pf[kt2 * 4]), f2bf(pf[kt2 * 4 + 1]),
                     f2bf(pf[kt2 * 4 + 2]), f2bf(pf[kt2 * 4 + 3])};
          *(u16x4*)(plw + (kt2 * 2 + (g >> 1)) * 256 + wb) = o;
        }
      }
      asm volatile("s_waitcnt lgkmcnt(0)" ::: "memory");

      // PV: acc[dt] += P(16x64) * V(64x16 slice dt); all reads linear
      bf16x8 pa0 = *(const bf16x8*)(plw + g * 256 + q15 * 16);
      bf16x8 pa1 = *(const bf16x8*)(plw + (4 + g) * 256 + q15 * 16);
      __builtin_amdgcn_s_setprio(1);
#pragma unroll
      for (int dt = 0; dt < 8; ++dt) {
        bf16x8 vb0 = *(const bf16x8*)(kvtb + dt * 1024 + l16);
        bf16x8 vb1 = *(const bf16x8*)(kvtb + (8 + dt) * 1024 + l16);
        acc[dt] = mfma16(pa0, vb0, acc[dt]);
        acc[dt] = mfma16(pa1, vb1, acc[dt]);
      }
      __builtin_amdgcn_s_setprio(0);

      // tile(s+1) loads (issued a full step ago) must be done; then one
      // barrier: (a) everyone finished reading tile s -> its buffers are
      // reusable, (b) everyone's waits done -> tile s+1 readable by all.
      if (s + 1 < nt) asm volatile("s_waitcnt vmcnt(0)" ::: "memory");
      __builtin_amdgcn_s_barrier();
      asm volatile("" ::: "memory");
      if (s + 2 < nt) {   // refill the buffers tile s occupied
        STAGE_KV(s & 1, s + 1);     // TIDX(s+2) = s+1
        STAGE_KVT(s & 1, s + 1);
      }
    }

    // combine g-group partial sums, normalize, write out
    lrun += __shfl_xor(lrun, 16);
    lrun += __shfl_xor(lrun, 32);
    const float inv = 1.f / lrun;
    float ir[4];
#pragma unroll
    for (int r = 0; r < 4; ++r) ir[r] = __shfl(inv, g * 4 + r);

    float* ob = out + ((size_t)b * TL + qt * 64 + 16 * w) * TE + h * TD;
#pragma unroll
    for (int dt = 0; dt < 8; ++dt)
#pragma unroll
      for (int r = 0; r < 4; ++r)
        ob[(g * 4 + r) * TE + dt * 16 + q15] = acc[dt][r] * ir[r];
    // next segment's prologue stages are safe: all waves passed the final
    // step barrier (no LDS access in this epilogue).
  }
}

// ---------------- fallback (v1-style, self-contained, no ws needed) ---------
__device__ __forceinline__ bf16x8 ld256s(const unsigned short* base, int row, int inrow) {
  const int off = (row * 256 + inrow) ^ ((row & 7) << 4);
  return *(const bf16x8*)((const char*)base + off);
}
__device__ __forceinline__ bf16x8 ld128s(const unsigned short* base, int row, int inrow) {
  const int off = (row * 128 + inrow) ^ ((row & 7) << 4);
  return *(const bf16x8*)((const char*)base + off);
}

__device__ __forceinline__ void stage_tile_fb(const float* __restrict__ src,
                                              unsigned short* kv, unsigned short* kvt,
                                              int t) {
  const int kr = (t >> 4) << 2;
  const int d0 = (t & 15) << 3;
  unsigned short c[4][8];
#pragma unroll
  for (int rr = 0; rr < 4; ++rr) {
    const float* p = src + (kr + rr) * TE + d0;
    const float4 a = *(const float4*)p;
    const float4 b = *(const float4*)(p + 4);
    c[rr][0] = f2bf(a.x); c[rr][1] = f2bf(a.y); c[rr][2] = f2bf(a.z); c[rr][3] = f2bf(a.w);
    c[rr][4] = f2bf(b.x); c[rr][5] = f2bf(b.y); c[rr][6] = f2bf(b.z); c[rr][7] = f2bf(b.w);
  }
#pragma unroll
  for (int rr = 0; rr < 4; ++rr) {
    const int r = kr + rr;
    u16x8 o = {c[rr][0], c[rr][1], c[rr][2], c[rr][3],
               c[rr][4], c[rr][5], c[rr][6], c[rr][7]};
    const int off = (r * 256 + d0 * 2) ^ ((r & 7) << 4);
    *(u16x8*)((char*)kv + off) = o;
  }
#pragma unroll
  for (int cc = 0; cc < 8; ++cc) {
    const int d = d0 + cc;
    u16x4 o = {c[0][cc], c[1][cc], c[2][cc], c[3][cc]};
    const int off = (d * 128 + kr * 2) ^ ((d & 7) << 4);
    *(u16x4*)((char*)kvt + off) = o;
  }
}

__global__ void __launch_bounds__(256)
evo_attn(const float* __restrict__ x, float* __restrict__ out) {
  __shared__ unsigned short kv[KB * TD];
  __shared__ unsigned short kvt[TD * KB];
  __shared__ unsigned short pl[4 * 16 * KB];

  const int t = threadIdx.x;
  const int lane = t & 63;
  const int w = t >> 6;
  const int g = lane >> 4;
  const int q15 = lane & 15;

  const int bh = blockIdx.x & 31;
  const int qt = 31 - (blockIdx.x >> 5);
  const int b = bh >> 4;
  const int h = bh & 15;
  const float* xb = x + (size_t)b * TL * TE + h * TD;
  const int q0 = qt * KB;

  stage_tile_fb(xb + (size_t)q0 * TE, kv, kvt, t);
  __syncthreads();

  bf16x8 qf[4];
#pragma unroll
  for (int c = 0; c < 4; ++c)
    qf[c] = ld256s(kv, 16 * w + q15, c * 64 + g * 16);

  f32x4 acc[8];
#pragma unroll
  for (int dt = 0; dt < 8; ++dt) acc[dt] = (f32x4){0.f, 0.f, 0.f, 0.f};
  float mrun = -1e30f;
  float lrun = 0.f;
  unsigned short* plw = pl + w * (16 * KB);

  for (int s = 0; s <= qt; ++s) {
    if (s > 0) {
      __syncthreads();
      stage_tile_fb(xb + (size_t)(s - 1) * KB * TE, kv, kvt, t);
      __syncthreads();
    }
    float sv[16];
#pragma unroll
    for (int kt2 = 0; kt2 < 4; ++kt2) {
      f32x4 st = (f32x4){0.f, 0.f, 0.f, 0.f};
#pragma unroll
      for (int c = 0; c < 4; ++c) {
        bf16x8 kf = ld256s(kv, kt2 * 16 + q15, c * 64 + g * 16);
        st = mfma16(kf, qf[c], st);
      }
#pragma unroll
      for (int r = 0; r < 4; ++r) sv[kt2 * 4 + r] = st[r] * SCALE_LOG2E;
    }
    if (s == 0) {
      const int qrel = 16 * w + q15;
#pragma unroll
      for (int kt2 = 0; kt2 < 4; ++kt2)
#pragma unroll
        for (int r = 0; r < 4; ++r)
          if (kt2 * 16 + g * 4 + r > qrel) sv[kt2 * 4 + r] = -1e30f;
    }
    float tmax = sv[0];
#pragma unroll
    for (int i = 1; i < 16; ++i) tmax = fmaxf(tmax, sv[i]);
    tmax = fmaxf(tmax, __shfl_xor(tmax, 16));
    tmax = fmaxf(tmax, __shfl_xor(tmax, 32));
    const float mnew = fmaxf(mrun, tmax);
    const float al = exp2f(mrun - mnew);
    mrun = mnew;
    float psum = 0.f;
    unsigned short pb[16];
#pragma unroll
    for (int i = 0; i < 16; ++i) {
      const float p = exp2f(sv[i] - mnew);
      psum += p;
      pb[i] = f2bf(p);
    }
    lrun = lrun * al + psum;
#pragma unroll
    for (int kt2 = 0; kt2 < 4; ++kt2) {
      u16x4 o = {pb[kt2 * 4], pb[kt2 * 4 + 1], pb[kt2 * 4 + 2], pb[kt2 * 4 + 3]};
      const int off = (q15 * 128 + kt2 * 32 + g * 8) ^ ((q15 & 7) << 4);
      *(u16x4*)((char*)plw + off) = o;
    }
    asm volatile("s_waitcnt lgkmcnt(0)" ::: "memory");
    float ar[4];
#pragma unroll
    for (int r = 0; r < 4; ++r) ar[r] = __shfl(al, g * 4 + r);
#pragma unroll
    for (int dt = 0; dt < 8; ++dt)
#pragma unroll
      for (int r = 0; r < 4; ++r) acc[dt][r] *= ar[r];
    bf16x8 pa0 = ld128s(plw, q15, g * 16);
    bf16x8 pa1 = ld128s(plw, q15, 64 + g * 16);
#pragma unroll
    for (int dt = 0; dt < 8; ++dt) {
      bf16x8 vb0 = ld128s(kvt, dt * 16 + q15, g * 16);
      bf16x8 vb1 = ld128s(kvt, dt * 16 + q15, 64 + g * 16);
      acc[dt] = mfma16(pa0, vb0, acc[dt]);
      acc[dt] = mfma16(pa1, vb1, acc[dt]);
    }
  }

  lrun += __shfl_xor(lrun, 16);
  lrun += __shfl_xor(lrun, 32);
  const float inv = 1.f / lrun;
  float ir[4];
#pragma unroll
  for (int r = 0; r < 4; ++r) ir[r] = __shfl(inv, g * 4 + r);
  float* ob = out + ((size_t)b * TL + q0 + 16 * w) * TE + h * TD;
#pragma unroll
  for (int dt = 0; dt < 8; ++dt)
#pragma unroll
    for (int r = 0; r < 4; ++r)
      ob[(g * 4 + r) * TE + dt * 16 + q15] = acc[dt][r] * ir[r];
}

extern "C" void kernel_launch(void* const* d_in, const int* in_sizes, int n_in,
                              void* d_out, int out_size, void* d_ws, size_t ws_size,
                              hipStream_t stream) {
  const float* x = (const float*)d_in[0];
  float* out = (float*)d_out;
  (void)in_sizes; (void)n_in; (void)out_size;
  if (ws_size >= (size_t)WS_NEED) {
    char* wsb = (char*)d_ws;
    prepack<<<dim3(1024), dim3(256), 0, stream>>>(x, wsb);
    evo_attn8<<<dim3(512), dim3(256), 0, stream>>>(wsb, out);
  } else {
    evo_attn<<<dim3(1024), dim3(256), 0, stream>>>(x, out);
  }
}

// Round 17
// 88.384 us; speedup vs baseline: 1.7464x; 1.0089x over previous
//
#include <hip/hip_runtime.h>
#include <hip/hip_bf16.h>

// EvoAttn: causal self-attention with Q=K=V = x.reshape(B,L,H,D).
// B=2 H=16 L=2048 D=128, fp32 in/out, bf16 MFMA compute.
// v17 = v16 minus s_setprio (lockstep-harmful per m190) + max3-shaped
//       reductions. Main structure (v15/v16, 78us) unchanged.

#define TL 2048
#define TE 2048
#define TD 128
#define KB 64
#define NTILES 32                          // TL / KB
#define TILE_B 16384                       // 64*128*2 bytes
#define KV_REGION (32 * NTILES * TILE_B)   // 16 MB per layout
#define WS_NEED (2u * (unsigned)KV_REGION) // 32 MB

typedef __attribute__((ext_vector_type(8))) short bf16x8;
typedef __attribute__((ext_vector_type(4))) float f32x4;
typedef __attribute__((ext_vector_type(8))) unsigned short u16x8;
typedef __attribute__((ext_vector_type(4))) unsigned short u16x4;

// (1/sqrt(128)) * log2(e)
#define SCALE_LOG2E 0.12751879f

__device__ __forceinline__ unsigned short f2bf(float f) {
  __hip_bfloat16 h = __float2bfloat16(f);
  return __builtin_bit_cast(unsigned short, h);
}

__device__ __forceinline__ f32x4 mfma16(bf16x8 a, bf16x8 b, f32x4 c) {
  return __builtin_amdgcn_mfma_f32_16x16x32_bf16(a, b, c, 0, 0, 0);
}

__device__ __forceinline__ void gl_lds16(const void* g, void* l) {
  __builtin_amdgcn_global_load_lds(
      (__attribute__((address_space(1))) void*)(g),
      (__attribute__((address_space(3))) void*)(l), 16, 0, 0);
}

// ws layout (per tile bid = bh*32 + kt):
// K region: 16B frag (kt2,c,g,q15) at ((kt2*4+c)*64 + g*16 + q15)*16
//   holding K[kt2*16+q15][c*32+g*8 .. +8).
// V region: 16B frag (half,dt,g,q15) at ((half*8+dt)*64 + g*16 + q15)*16
//   holding V[k=half*32+g*8+j][d=dt*16+q15].
// Prepack: build both images in LDS (scattered small writes cheap there),
// then copy out with fully-coalesced 64B-per-thread stores.
__global__ void __launch_bounds__(256)
prepack(const float* __restrict__ x, char* __restrict__ wsb) {
  __shared__ unsigned short kimg[8192];   // 16 KB K-fragment image
  __shared__ unsigned short vimg[8192];   // 16 KB V-fragment image

  const int bid = blockIdx.x;            // bh*32 + kt
  const int kt = bid & 31;
  const int bh = bid >> 5;
  const int b = bh >> 4;
  const int h = bh & 15;
  const float* src = x + (size_t)b * TL * TE + h * TD + (size_t)kt * KB * TE;
  const int t = threadIdx.x;
  const int kr = (t >> 4) << 2;          // 4 consecutive k-rows
  const int d0 = (t & 15) << 3;          // 8 d-cols
  unsigned short c[4][8];
#pragma unroll
  for (int rr = 0; rr < 4; ++rr) {
    const float* p = src + (kr + rr) * TE + d0;
    const float4 a = *(const float4*)p;
    const float4 bb = *(const float4*)(p + 4);
    c[rr][0] = f2bf(a.x);  c[rr][1] = f2bf(a.y);  c[rr][2] = f2bf(a.z);  c[rr][3] = f2bf(a.w);
    c[rr][4] = f2bf(bb.x); c[rr][5] = f2bf(bb.y); c[rr][6] = f2bf(bb.z); c[rr][7] = f2bf(bb.w);
  }
  // K fragment image (LDS)
  const int kt2 = kr >> 4;
  const int q0r = kr & 15;
  const int cc_ = (t & 15) >> 2;
  const int gg_ = (t & 15) & 3;
#pragma unroll
  for (int rr = 0; rr < 4; ++rr) {
    u16x8 o = {c[rr][0], c[rr][1], c[rr][2], c[rr][3],
               c[rr][4], c[rr][5], c[rr][6], c[rr][7]};
    const int off = (((kt2 * 4 + cc_) * 64 + gg_ * 16 + (q0r + rr)) << 4);
    *(u16x8*)((char*)kimg + off) = o;
  }
  // V fragment image (LDS)
  const int half = kr >> 5;
  const int g = (kr >> 3) & 3;
  const int j0 = kr & 7;                 // 0 or 4
#pragma unroll
  for (int cc = 0; cc < 8; ++cc) {
    const int d = d0 + cc;
    u16x4 o = {c[0][cc], c[1][cc], c[2][cc], c[3][cc]};   // k = kr..kr+3
    const int off = (((half * 8 + (d >> 4)) * 64 + g * 16 + (d & 15)) << 4) + j0 * 2;
    *(u16x4*)((char*)vimg + off) = o;
  }
  __syncthreads();

  // coalesced copy-out: 64B per thread per image
  char* gkv = wsb + (size_t)bid * TILE_B;
  char* gkt = wsb + KV_REGION + (size_t)bid * TILE_B;
  const char* ki = (const char*)kimg;
  const char* vi = (const char*)vimg;
#pragma unroll
  for (int i = 0; i < 4; ++i) {
    *(u16x8*)(gkv + t * 64 + i * 16) = *(const u16x8*)(ki + t * 64 + i * 16);
    *(u16x8*)(gkt + t * 64 + i * 16) = *(const u16x8*)(vi + t * 64 + i * 16);
  }
}

// ---------------- main attention kernel: pair (a, 31-a), 33 steps/block -----
__global__ void __launch_bounds__(256)
evo_attn8(const char* __restrict__ wsb, float* __restrict__ out) {
  // kv0 | kv1 | kvt0 | kvt1 | pl(4 waves x 2KB) = 72 KB -> 2 blocks/CU
  __shared__ char smem[4 * TILE_B + 8192];

  const int t = threadIdx.x;
  const int lane = t & 63;
  const int w = t >> 6;        // wave 0..3, owns q rows [q0+16w, q0+16w+16)
  const int g = lane >> 4;
  const int q15 = lane & 15;

  const int blk = blockIdx.x;            // 512 blocks
  const int bh = (blk & 7) * 4 + (blk >> 7);   // XCD-affine
  const int a = (blk >> 3) & 15;         // pair: q-tiles a and 31-a
  const int b = bh >> 4;
  const int h = bh & 15;

  const char* gkv = wsb + (size_t)bh * (NTILES * TILE_B);
  const char* gkt = wsb + KV_REGION + (size_t)bh * (NTILES * TILE_B);
  char* plw = smem + 4 * TILE_B + w * 2048;
  const int l16 = lane * 16;

#define STAGE_KV(BUFI, KT)                                                 \
  {                                                                        \
    char* dst_ = smem + (BUFI) * TILE_B + (t >> 6) * 1024;                 \
    const char* src_ = gkv + (size_t)(KT) * TILE_B + t * 16;               \
    _Pragma("unroll")                                                      \
    for (int i_ = 0; i_ < 4; ++i_) gl_lds16(src_ + i_ * 4096, dst_ + i_ * 4096); \
  }
#define STAGE_KVT(BUFI, KT)                                                \
  {                                                                        \
    char* dst_ = smem + (2 + (BUFI)) * TILE_B + (t >> 6) * 1024;           \
    const char* src_ = gkt + (size_t)(KT) * TILE_B + t * 16;               \
    _Pragma("unroll")                                                      \
    for (int i_ = 0; i_ < 4; ++i_) gl_lds16(src_ + i_ * 4096, dst_ + i_ * 4096); \
  }

#pragma unroll 1
  for (int seg = 0; seg < 2; ++seg) {
    const int qt = seg ? (31 - a) : a;   // q-tile (64 rows at 64*qt)
    const int nt = qt + 1;

    // prologue: stage tiles for s=0 (diag) and s=1
    STAGE_KV(0, qt);
    STAGE_KVT(0, qt);
    if (nt > 1) { STAGE_KV(1, 0); STAGE_KVT(1, 0); }
    if (nt > 1) asm volatile("s_waitcnt vmcnt(8)" ::: "memory");
    else        asm volatile("s_waitcnt vmcnt(0)" ::: "memory");
    __builtin_amdgcn_s_barrier();
    asm volatile("" ::: "memory");

    // Q fragments from kv buf0 (diag tile IS the Q tile); kt2 = w
    bf16x8 qf[4];
#pragma unroll
    for (int c = 0; c < 4; ++c)
      qf[c] = *(const bf16x8*)(smem + (w * 4 + c) * 1024 + l16);

    f32x4 acc[8];
#pragma unroll
    for (int dt = 0; dt < 8; ++dt) acc[dt] = (f32x4){0.f, 0.f, 0.f, 0.f};
    float mrun = -1e30f;   // raw score domain
    float lrun = 0.f;

    for (int s = 0; s < nt; ++s) {
      const char* kv = smem + (s & 1) * TILE_B;
      const char* kvtb = smem + (2 + (s & 1)) * TILE_B;

      // QK^T: lane (g,q15) holds S[k=kt2*16+g*4+r][q=16w+q15] (raw)
      float pf[16];
#pragma unroll
      for (int kt2 = 0; kt2 < 4; ++kt2) {
        f32x4 st = (f32x4){0.f, 0.f, 0.f, 0.f};
#pragma unroll
        for (int c = 0; c < 4; ++c) {
          bf16x8 kf = *(const bf16x8*)(kv + (kt2 * 4 + c) * 1024 + l16);
          st = mfma16(kf, qf[c], st);
        }
#pragma unroll
        for (int r = 0; r < 4; ++r) pf[kt2 * 4 + r] = st[r];
      }

      if (s == 0) {  // diagonal causal mask
        const int qrel = 16 * w + q15;
#pragma unroll
        for (int kt2 = 0; kt2 < 4; ++kt2)
#pragma unroll
          for (int r = 0; r < 4; ++r)
            if (kt2 * 16 + g * 4 + r > qrel) pf[kt2 * 4 + r] = -1e30f;
      }

      // online softmax, defer-max fast path; max3-shaped tree
      float m0 = fmaxf(fmaxf(pf[0], pf[1]), pf[2]);
      float m1 = fmaxf(fmaxf(pf[3], pf[4]), pf[5]);
      float m2 = fmaxf(fmaxf(pf[6], pf[7]), pf[8]);
      float m3 = fmaxf(fmaxf(pf[9], pf[10]), pf[11]);
      float m4 = fmaxf(fmaxf(pf[12], pf[13]), pf[14]);
      float t0 = fmaxf(fmaxf(m0, m1), m2);
      float t1 = fmaxf(fmaxf(m3, m4), pf[15]);
      float tmax = fmaxf(t0, t1);
      tmax = fmaxf(tmax, __shfl_xor(tmax, 16));
      tmax = fmaxf(tmax, __shfl_xor(tmax, 32));

      if (__all(tmax <= mrun)) {
        const float nmc = -mrun * SCALE_LOG2E;
#pragma unroll
        for (int i = 0; i < 16; ++i) pf[i] = exp2f(fmaf(pf[i], SCALE_LOG2E, nmc));
      } else {
        const float mnew = fmaxf(mrun, tmax);
        const float al = exp2f((mrun - mnew) * SCALE_LOG2E);
        mrun = mnew;
        const float nmc = -mnew * SCALE_LOG2E;
#pragma unroll
        for (int i = 0; i < 16; ++i) pf[i] = exp2f(fmaf(pf[i], SCALE_LOG2E, nmc));
        lrun *= al;
        float ar[4];
#pragma unroll
        for (int r = 0; r < 4; ++r) ar[r] = __shfl(al, g * 4 + r);
#pragma unroll
        for (int dt = 0; dt < 8; ++dt)
#pragma unroll
          for (int r = 0; r < 4; ++r) acc[dt][r] *= ar[r];
      }
      {
        float s01 = (pf[0] + pf[1]) + (pf[2] + pf[3]);
        float s23 = (pf[4] + pf[5]) + (pf[6] + pf[7]);
        float s45 = (pf[8] + pf[9]) + (pf[10] + pf[11]);
        float s67 = (pf[12] + pf[13]) + (pf[14] + pf[15]);
        lrun += (s01 + s23) + (s45 + s67);
      }

      // P -> per-wave LDS as [k-octet m][q15] 16B units (conflict-free read)
      {
        const int wb = q15 * 16 + (g & 1) * 8;
#pragma unroll
        for (int kt2 = 0; kt2 < 4; ++kt2) {
          u16x4 o = {f2bf(pf[kt2 * 4]), f2bf(pf[kt2 * 4 + 1]),
                     f2bf(pf[kt2 * 4 + 2]), f2bf(pf[kt2 * 4 + 3])};
          *(u16x4*)(plw + (kt2 * 2 + (g >> 1)) * 256 + wb) = o;
        }
      }
      asm volatile("s_waitcnt lgkmcnt(0)" ::: "memory");

      // PV: acc[dt] += P(16x64) * V(64x16 slice dt); all reads linear
      bf16x8 pa0 = *(const bf16x8*)(plw + g * 256 + q15 * 16);
      bf16x8 pa1 = *(const bf16x8*)(plw + (4 + g) * 256 + q15 * 16);
#pragma unroll
      for (int dt = 0; dt < 8; ++dt) {
        bf16x8 vb0 = *(const bf16x8*)(kvtb + dt * 1024 + l16);
        bf16x8 vb1 = *(const bf16x8*)(kvtb + (8 + dt) * 1024 + l16);
        acc[dt] = mfma16(pa0, vb0, acc[dt]);
        acc[dt] = mfma16(pa1, vb1, acc[dt]);
      }

      // tile(s+1) loads (issued a full step ago) must be done; then one
      // barrier: (a) everyone finished reading tile s -> buffers reusable,
      // (b) everyone's waits done -> tile s+1 readable by all.
      if (s + 1 < nt) asm volatile("s_waitcnt vmcnt(0)" ::: "memory");
      __builtin_amdgcn_s_barrier();
      asm volatile("" ::: "memory");
      if (s + 2 < nt) {   // refill the buffers tile s occupied
        STAGE_KV(s & 1, s + 1);     // tile for step s+2 is s+1
        STAGE_KVT(s & 1, s + 1);
      }
    }

    // combine g-group partial sums, normalize, write out
    lrun += __shfl_xor(lrun, 16);
    lrun += __shfl_xor(lrun, 32);
    const float inv = 1.f / lrun;
    float ir[4];
#pragma unroll
    for (int r = 0; r < 4; ++r) ir[r] = __shfl(inv, g * 4 + r);

    float* ob = out + ((size_t)b * TL + qt * 64 + 16 * w) * TE + h * TD;
#pragma unroll
    for (int dt = 0; dt < 8; ++dt)
#pragma unroll
      for (int r = 0; r < 4; ++r)
        ob[(g * 4 + r) * TE + dt * 16 + q15] = acc[dt][r] * ir[r];
    // next segment's prologue stages are safe: all waves passed the final
    // step barrier (no LDS access in this epilogue).
  }
}

// ---------------- fallback (v1-style, self-contained, no ws needed) ---------
__device__ __forceinline__ bf16x8 ld256s(const unsigned short* base, int row, int inrow) {
  const int off = (row * 256 + inrow) ^ ((row & 7) << 4);
  return *(const bf16x8*)((const char*)base + off);
}
__device__ __forceinline__ bf16x8 ld128s(const unsigned short* base, int row, int inrow) {
  const int off = (row * 128 + inrow) ^ ((row & 7) << 4);
  return *(const bf16x8*)((const char*)base + off);
}

__device__ __forceinline__ void stage_tile_fb(const float* __restrict__ src,
                                              unsigned short* kv, unsigned short* kvt,
                                              int t) {
  const int kr = (t >> 4) << 2;
  const int d0 = (t & 15) << 3;
  unsigned short c[4][8];
#pragma unroll
  for (int rr = 0; rr < 4; ++rr) {
    const float* p = src + (kr + rr) * TE + d0;
    const float4 a = *(const float4*)p;
    const float4 b = *(const float4*)(p + 4);
    c[rr][0] = f2bf(a.x); c[rr][1] = f2bf(a.y); c[rr][2] = f2bf(a.z); c[rr][3] = f2bf(a.w);
    c[rr][4] = f2bf(b.x); c[rr][5] = f2bf(b.y); c[rr][6] = f2bf(b.z); c[rr][7] = f2bf(b.w);
  }
#pragma unroll
  for (int rr = 0; rr < 4; ++rr) {
    const int r = kr + rr;
    u16x8 o = {c[rr][0], c[rr][1], c[rr][2], c[rr][3],
               c[rr][4], c[rr][5], c[rr][6], c[rr][7]};
    const int off = (r * 256 + d0 * 2) ^ ((r & 7) << 4);
    *(u16x8*)((char*)kv + off) = o;
  }
#pragma unroll
  for (int cc = 0; cc < 8; ++cc) {
    const int d = d0 + cc;
    u16x4 o = {c[0][cc], c[1][cc], c[2][cc], c[3][cc]};
    const int off = (d * 128 + kr * 2) ^ ((d & 7) << 4);
    *(u16x4*)((char*)kvt + off) = o;
  }
}

__global__ void __launch_bounds__(256)
evo_attn(const float* __restrict__ x, float* __restrict__ out) {
  __shared__ unsigned short kv[KB * TD];
  __shared__ unsigned short kvt[TD * KB];
  __shared__ unsigned short pl[4 * 16 * KB];

  const int t = threadIdx.x;
  const int lane = t & 63;
  const int w = t >> 6;
  const int g = lane >> 4;
  const int q15 = lane & 15;

  const int bh = blockIdx.x & 31;
  const int qt = 31 - (blockIdx.x >> 5);
  const int b = bh >> 4;
  const int h = bh & 15;
  const float* xb = x + (size_t)b * TL * TE + h * TD;
  const int q0 = qt * KB;

  stage_tile_fb(xb + (size_t)q0 * TE, kv, kvt, t);
  __syncthreads();

  bf16x8 qf[4];
#pragma unroll
  for (int c = 0; c < 4; ++c)
    qf[c] = ld256s(kv, 16 * w + q15, c * 64 + g * 16);

  f32x4 acc[8];
#pragma unroll
  for (int dt = 0; dt < 8; ++dt) acc[dt] = (f32x4){0.f, 0.f, 0.f, 0.f};
  float mrun = -1e30f;
  float lrun = 0.f;
  unsigned short* plw = pl + w * (16 * KB);

  for (int s = 0; s <= qt; ++s) {
    if (s > 0) {
      __syncthreads();
      stage_tile_fb(xb + (size_t)(s - 1) * KB * TE, kv, kvt, t);
      __syncthreads();
    }
    float sv[16];
#pragma unroll
    for (int kt2 = 0; kt2 < 4; ++kt2) {
      f32x4 st = (f32x4){0.f, 0.f, 0.f, 0.f};
#pragma unroll
      for (int c = 0; c < 4; ++c) {
        bf16x8 kf = ld256s(kv, kt2 * 16 + q15, c * 64 + g * 16);
        st = mfma16(kf, qf[c], st);
      }
#pragma unroll
      for (int r = 0; r < 4; ++r) sv[kt2 * 4 + r] = st[r] * SCALE_LOG2E;
    }
    if (s == 0) {
      const int qrel = 16 * w + q15;
#pragma unroll
      for (int kt2 = 0; kt2 < 4; ++kt2)
#pragma unroll
        for (int r = 0; r < 4; ++r)
          if (kt2 * 16 + g * 4 + r > qrel) sv[kt2 * 4 + r] = -1e30f;
    }
    float tmax = sv[0];
#pragma unroll
    for (int i = 1; i < 16; ++i) tmax = fmaxf(tmax, sv[i]);
    tmax = fmaxf(tmax, __shfl_xor(tmax, 16));
    tmax = fmaxf(tmax, __shfl_xor(tmax, 32));
    const float mnew = fmaxf(mrun, tmax);
    const float al = exp2f(mrun - mnew);
    mrun = mnew;
    float psum = 0.f;
    unsigned short pb[16];
#pragma unroll
    for (int i = 0; i < 16; ++i) {
      const float p = exp2f(sv[i] - mnew);
      psum += p;
      pb[i] = f2bf(p);
    }
    lrun = lrun * al + psum;
#pragma unroll
    for (int kt2 = 0; kt2 < 4; ++kt2) {
      u16x4 o = {pb[kt2 * 4], pb[kt2 * 4 + 1], pb[kt2 * 4 + 2], pb[kt2 * 4 + 3]};
      const int off = (q15 * 128 + kt2 * 32 + g * 8) ^ ((q15 & 7) << 4);
      *(u16x4*)((char*)plw + off) = o;
    }
    asm volatile("s_waitcnt lgkmcnt(0)" ::: "memory");
    float ar[4];
#pragma unroll
    for (int r = 0; r < 4; ++r) ar[r] = __shfl(al, g * 4 + r);
#pragma unroll
    for (int dt = 0; dt < 8; ++dt)
#pragma unroll
      for (int r = 0; r < 4; ++r) acc[dt][r] *= ar[r];
    bf16x8 pa0 = ld128s(plw, q15, g * 16);
    bf16x8 pa1 = ld128s(plw, q15, 64 + g * 16);
#pragma unroll
    for (int dt = 0; dt < 8; ++dt) {
      bf16x8 vb0 = ld128s(kvt, dt * 16 + q15, g * 16);
      bf16x8 vb1 = ld128s(kvt, dt * 16 + q15, 64 + g * 16);
      acc[dt] = mfma16(pa0, vb0, acc[dt]);
      acc[dt] = mfma16(pa1, vb1, acc[dt]);
    }
  }

  lrun += __shfl_xor(lrun, 16);
  lrun += __shfl_xor(lrun, 32);
  const float inv = 1.f / lrun;
  float ir[4];
#pragma unroll
  for (int r = 0; r < 4; ++r) ir[r] = __shfl(inv, g * 4 + r);
  float* ob = out + ((size_t)b * TL + q0 + 16 * w) * TE + h * TD;
#pragma unroll
  for (int dt = 0; dt < 8; ++dt)
#pragma unroll
    for (int r = 0; r < 4; ++r)
      ob[(g * 4 + r) * TE + dt * 16 + q15] = acc[dt][r] * ir[r];
}

extern "C" void kernel_launch(void* const* d_in, const int* in_sizes, int n_in,
                              void* d_out, int out_size, void* d_ws, size_t ws_size,
                              hipStream_t stream) {
  const float* x = (const float*)d_in[0];
  float* out = (float*)d_out;
  (void)in_sizes; (void)n_in; (void)out_size;
  if (ws_size >= (size_t)WS_NEED) {
    char* wsb = (char*)d_ws;
    prepack<<<dim3(1024), dim3(256), 0, stream>>>(x, wsb);
    evo_attn8<<<dim3(512), dim3(256), 0, stream>>>(wsb, out);
  } else {
    evo_attn<<<dim3(1024), dim3(256), 0, stream>>>(x, out);
  }
}